// Round 3
// baseline (445.045 us; speedup 1.0000x reference)
//
#include <hip/hip_runtime.h>

// ---------------------------------------------------------------------------
// MDNV2 fused kernels for MI355X (gfx950) — round 3
//
// vs round 2: pair_kernel re-blocked for occupancy. 64 rows/block but 8 waves
// (512 thr); wave = (row-half, frag-quarter): acc 7x2 f32x4 = 56 VGPR
// (was 112) -> __launch_bounds__(512,4) => 4 waves/SIMD (16 waves/CU).
// Sig/mu stores overlapped with pi-softmax barriers.
// ---------------------------------------------------------------------------

typedef __attribute__((ext_vector_type(8))) short bf16x8;
typedef __attribute__((ext_vector_type(4))) float f32x4;
typedef __attribute__((ext_vector_type(4))) unsigned int u32x4;

#define M_TOT 327680
#define N2A 448          // padded head rows: pi[0,144) sig[144,288) mu[288,432) pad

__device__ __forceinline__ unsigned short f2bf(float f) {
    union { float f; unsigned int u; } v; v.f = f;
    unsigned int r = (v.u + 0x7FFFu + ((v.u >> 16) & 1u)) >> 16;  // RNE
    return (unsigned short)r;
}

__device__ __forceinline__ float eluf(float y) {
    return fmaxf(y, 0.f) + __expf(fminf(y, 0.f)) - 1.f;
}

__device__ __forceinline__ unsigned packbf(float y0, float y1) {
    return (__float_as_uint(y1) & 0xFFFF0000u) | (__float_as_uint(y0) >> 16);
}

// ---------------------------------------------------------------------------
// prep_weights (unchanged layout):
//   W1T @0       : [256 n][256 k] bf16
//   W2T @131072  : [448 n][256 k] bf16
//   b2  @360448  : [448] f32
//   a1  @362240  : [256] f32
//   cs  @363264  : [256] f32
//   Lq  @364544  : [768][256] f32
//   Pq  @1150976 : [6144][256] f32
// ---------------------------------------------------------------------------
__global__ void prep_weights(const float* __restrict__ W1, const float* __restrict__ b1,
                             const float* __restrict__ gamma, const float* __restrict__ beta,
                             const float* __restrict__ rmean, const float* __restrict__ rvar,
                             const float* __restrict__ Wpi, const float* __restrict__ bpi,
                             const float* __restrict__ Wsig, const float* __restrict__ bsig,
                             const float* __restrict__ Wmu, const float* __restrict__ bmu,
                             unsigned short* __restrict__ W1T, unsigned short* __restrict__ W2T,
                             float* __restrict__ b2, float* __restrict__ a1v, float* __restrict__ csv) {
    int idx = blockIdx.x * 256 + threadIdx.x;
    if (idx < N2A * 256) {                       // W2T[n][k]
        int n = idx >> 8, k = idx & 255;
        float v = 0.f;
        if (n < 140)                      v = Wpi [k * 140 + n];
        else if (n >= 144 && n < 284)     v = Wsig[k * 140 + (n - 144)];
        else if (n >= 288 && n < 428)     v = Wmu [k * 140 + (n - 288)];
        W2T[idx] = f2bf(v);
    }
    if (idx < 256 * 256) {                       // W1T[n][k] = W1[k][n]
        int n = idx >> 8, k = idx & 255;
        W1T[idx] = f2bf(W1[k * 256 + n]);
    }
    if (idx < N2A) {
        float v = 0.f;
        if (idx < 140)                      v = bpi [idx];
        else if (idx >= 144 && idx < 284)   v = bsig[idx - 144];
        else if (idx >= 288 && idx < 428)   v = bmu [idx - 288];
        b2[idx] = v;
    }
    if (idx < 256) {
        float s = gamma[idx] * rsqrtf(rvar[idx] + 1e-5f);
        a1v[idx] = s;
        csv[idx] = s * (b1[idx] - rmean[idx]) + beta[idx];
    }
}

// ---------------------------------------------------------------------------
// node_gemm: Lq (with BN shift) and Pq (scale only) from h_l/h_p @ W1 halves
// ---------------------------------------------------------------------------
__global__ __launch_bounds__(256, 2) void node_gemm(
        const float* __restrict__ h_l, const float* __restrict__ h_p,
        const unsigned short* __restrict__ W1T,
        const float* __restrict__ a1v, const float* __restrict__ csv,
        float* __restrict__ Lq, float* __restrict__ Pq) {
    const int tid = threadIdx.x, lane = tid & 63, w = tid >> 6;
    const int cGrp = lane & 15, g = lane >> 4;
    const int row0 = blockIdx.x * 64;
    const bool isLig = row0 < 768;
    const float* src = isLig ? (h_l + (size_t)row0 * 128) : (h_p + (size_t)(row0 - 768) * 128);
    float*       dst = isLig ? (Lq + (size_t)row0 * 256) : (Pq + (size_t)(row0 - 768) * 256);
    const int koff = isLig ? 0 : 128;

    f32x4 acc[16];
    #pragma unroll
    for (int fn = 0; fn < 16; ++fn) acc[fn] = (f32x4){0.f, 0.f, 0.f, 0.f};

    #pragma unroll
    for (int fk = 0; fk < 4; ++fk) {
        const float* ap = src + (size_t)(w * 16 + cGrp) * 128 + fk * 32 + g * 8;
        f32x4 qa = *(const f32x4*)ap;
        f32x4 qb = *(const f32x4*)(ap + 4);
        bf16x8 af;
        af[0] = (short)f2bf(qa[0]); af[1] = (short)f2bf(qa[1]);
        af[2] = (short)f2bf(qa[2]); af[3] = (short)f2bf(qa[3]);
        af[4] = (short)f2bf(qb[0]); af[5] = (short)f2bf(qb[1]);
        af[6] = (short)f2bf(qb[2]); af[7] = (short)f2bf(qb[3]);
        #pragma unroll
        for (int fn = 0; fn < 16; ++fn) {
            bf16x8 bf = *(const bf16x8*)(W1T + (fn * 16 + cGrp) * 256 + koff + fk * 32 + g * 8);
            acc[fn] = __builtin_amdgcn_mfma_f32_16x16x32_bf16(af, bf, acc[fn], 0, 0, 0);
        }
    }
    #pragma unroll
    for (int fn = 0; fn < 16; ++fn) {
        int h = fn * 16 + cGrp;
        float s = a1v[h];
        float c0 = isLig ? csv[h] : 0.f;
        #pragma unroll
        for (int rg = 0; rg < 4; ++rg)
            dst[(size_t)(w * 16 + g * 4 + rg) * 256 + h] = s * acc[fn][rg] + c0;
    }
}

// ---------------------------------------------------------------------------
// pair_kernel: 64 pair-rows/block, 512 threads (8 waves).
//   wave w: wr = w>>2 row-half (32 rows, 2 rowsets), wf = w&3 frag-quarter
//   acc[7][2] f32x4 = 56 VGPR; launch_bounds(512,4) -> 16 waves/CU.
// ---------------------------------------------------------------------------
__global__ __launch_bounds__(512, 4) void pair_kernel(
        const float* __restrict__ Lq, const float* __restrict__ Pq,
        const unsigned short* __restrict__ W2T, const float* __restrict__ b2p,
        const float* __restrict__ lig_pos, const float* __restrict__ prot_pos,
        float* __restrict__ out_pi, float* __restrict__ out_sig, float* __restrict__ out_mu,
        float* __restrict__ out_dist, float* __restrict__ out_pb) {

    __shared__ __align__(16) unsigned short Xs[64 * 264];
    __shared__ float pmax[2][64];
    __shared__ float psum[2][64];

    const int tid = threadIdx.x, lane = tid & 63, w = tid >> 6;
    const int cGrp = lane & 15, g = lane >> 4;
    const int wr = w >> 2, wf = w & 3;
    const int m0 = blockIdx.x * 64;

    // ---- closed-form pair decode (block-uniform batch/ligand) ----
    unsigned int P = (unsigned int)m0 / 40960u;
    unsigned int r = (unsigned int)m0 % 40960u;
    int b, cl, cp0;
    if (r < 8192u) {
        b = 2 * (int)P; cl = 96 * (int)P + (int)(r >> 8); cp0 = 768 * (int)P + (int)(r & 255u);
    } else {
        unsigned int rr = r - 8192u;
        b = 2 * (int)P + 1; cl = 96 * (int)P + 32 + (int)(rr >> 9); cp0 = 768 * (int)P + 256 + (int)(rr & 511u);
    }

    // ---- phase 1: X = elu(Lq[cl] + Pq[cp]) -> LDS bf16, 512-thread split ----
    {
        const int xr = tid >> 3, c = tid & 7;                 // row, 32-col chunk
        const float* pq = Pq + (size_t)(cp0 + xr) * 256 + c * 32;
        const float* lq = Lq + (size_t)cl * 256 + c * 32;
        unsigned short* xrow = Xs + xr * 264 + c * 32;
        #pragma unroll
        for (int u = 0; u < 4; ++u) {
            f32x4 p0 = ((const f32x4*)pq)[2 * u];
            f32x4 p1 = ((const f32x4*)pq)[2 * u + 1];
            f32x4 l0 = ((const f32x4*)lq)[2 * u];
            f32x4 l1 = ((const f32x4*)lq)[2 * u + 1];
            float y0 = eluf(l0[0] + p0[0]), y1 = eluf(l0[1] + p0[1]);
            float y2 = eluf(l0[2] + p0[2]), y3 = eluf(l0[3] + p0[3]);
            float y4 = eluf(l1[0] + p1[0]), y5 = eluf(l1[1] + p1[1]);
            float y6 = eluf(l1[2] + p1[2]), y7 = eluf(l1[3] + p1[3]);
            u32x4 q;
            q[0] = packbf(y0, y1); q[1] = packbf(y2, y3);
            q[2] = packbf(y4, y5); q[3] = packbf(y6, y7);
            *(u32x4*)(xrow + u * 8) = q;
        }
    }
    __syncthreads();

    // ---- phase 2: GEMM2, wave owns frags fnBase..fnBase+6 x 32 rows ----
    f32x4 acc[7][2];
    #pragma unroll
    for (int i = 0; i < 7; ++i) {
        acc[i][0] = (f32x4){0.f, 0.f, 0.f, 0.f};
        acc[i][1] = (f32x4){0.f, 0.f, 0.f, 0.f};
    }
    const int fnBase = wf * 7;
    const int rowB = wr * 32;

    #pragma unroll
    for (int fk = 0; fk < 8; ++fk) {
        const int kb = fk * 32 + g * 8;
        bf16x8 af0 = *(const bf16x8*)&Xs[(rowB + cGrp) * 264 + kb];
        bf16x8 af1 = *(const bf16x8*)&Xs[(rowB + 16 + cGrp) * 264 + kb];
        #pragma unroll
        for (int i = 0; i < 7; ++i) {
            bf16x8 bf = *(const bf16x8*)(W2T + ((fnBase + i) * 16 + cGrp) * 256 + kb);
            acc[i][0] = __builtin_amdgcn_mfma_f32_16x16x32_bf16(af0, bf, acc[i][0], 0, 0, 0);
            acc[i][1] = __builtin_amdgcn_mfma_f32_16x16x32_bf16(af1, bf, acc[i][1], 0, 0, 0);
        }
    }

    // ---- bias add ----
    #pragma unroll
    for (int i = 0; i < 7; ++i) {
        float bb = b2p[(fnBase + i) * 16 + cGrp];
        #pragma unroll
        for (int rs = 0; rs < 2; ++rs)
            #pragma unroll
            for (int rg = 0; rg < 4; ++rg) acc[i][rs][rg] += bb;
    }

    // ---- pi partial max (waves wf<2) ----
    if (wf < 2) {
        float mx[2][4];
        #pragma unroll
        for (int rs = 0; rs < 2; ++rs)
            #pragma unroll
            for (int rg = 0; rg < 4; ++rg) mx[rs][rg] = -3.0e38f;
        #pragma unroll
        for (int i = 0; i < 7; ++i) {
            int fn = fnBase + i;
            if (fn < 9) {
                bool valid = (fn < 8) || (cGrp < 12);
                if (valid)
                    #pragma unroll
                    for (int rs = 0; rs < 2; ++rs)
                        #pragma unroll
                        for (int rg = 0; rg < 4; ++rg)
                            mx[rs][rg] = fmaxf(mx[rs][rg], acc[i][rs][rg]);
            }
        }
        #pragma unroll
        for (int rs = 0; rs < 2; ++rs)
            #pragma unroll
            for (int rg = 0; rg < 4; ++rg) {
                float v = mx[rs][rg];
                v = fmaxf(v, __shfl_xor(v, 1, 64));
                v = fmaxf(v, __shfl_xor(v, 2, 64));
                v = fmaxf(v, __shfl_xor(v, 4, 64));
                v = fmaxf(v, __shfl_xor(v, 8, 64));
                mx[rs][rg] = v;
            }
        if (cGrp == 0) {
            #pragma unroll
            for (int rs = 0; rs < 2; ++rs)
                #pragma unroll
                for (int rg = 0; rg < 4; ++rg)
                    pmax[wf][rowB + rs * 16 + g * 4 + rg] = mx[rs][rg];
        }
    }
    __syncthreads();

    // ---- pi exp + partial sums (wf<2) ----
    if (wf < 2) {
        float mxc[2][4], sm[2][4];
        #pragma unroll
        for (int rs = 0; rs < 2; ++rs)
            #pragma unroll
            for (int rg = 0; rg < 4; ++rg) {
                int rl = rowB + rs * 16 + g * 4 + rg;
                mxc[rs][rg] = fmaxf(pmax[0][rl], pmax[1][rl]);
                sm[rs][rg] = 0.f;
            }
        #pragma unroll
        for (int i = 0; i < 7; ++i) {
            int fn = fnBase + i;
            if (fn < 9) {
                bool valid = (fn < 8) || (cGrp < 12);
                #pragma unroll
                for (int rs = 0; rs < 2; ++rs)
                    #pragma unroll
                    for (int rg = 0; rg < 4; ++rg) {
                        float e = valid ? __expf(acc[i][rs][rg] - mxc[rs][rg]) : 0.f;
                        acc[i][rs][rg] = e;
                        sm[rs][rg] += e;
                    }
            }
        }
        #pragma unroll
        for (int rs = 0; rs < 2; ++rs)
            #pragma unroll
            for (int rg = 0; rg < 4; ++rg) {
                float v = sm[rs][rg];
                v += __shfl_xor(v, 1, 64);
                v += __shfl_xor(v, 2, 64);
                v += __shfl_xor(v, 4, 64);
                v += __shfl_xor(v, 8, 64);
                sm[rs][rg] = v;
            }
        if (cGrp == 0) {
            #pragma unroll
            for (int rs = 0; rs < 2; ++rs)
                #pragma unroll
                for (int rg = 0; rg < 4; ++rg)
                    psum[wf][rowB + rs * 16 + g * 4 + rg] = sm[rs][rg];
        }
    }

    // ---- sigma / mu stores (overlap with softmax exchange) ----
    #pragma unroll
    for (int i = 0; i < 7; ++i) {
        int fn = fnBase + i;
        if (fn >= 9 && fn < 27) {
            int n = fn * 16 + cGrp;
            bool isSig = fn < 18;
            int col = isSig ? (n - 144) : (n - 288);
            if (col < 140) {
                float addc = isSig ? 1.1f : 1.0f;
                float* outp = isSig ? out_sig : out_mu;
                #pragma unroll
                for (int rs = 0; rs < 2; ++rs)
                    #pragma unroll
                    for (int rg = 0; rg < 4; ++rg) {
                        float y = eluf(acc[i][rs][rg]) + addc;
                        outp[(size_t)(m0 + rowB + rs * 16 + g * 4 + rg) * 140 + col] = y;
                    }
            }
        }
    }

    // ---- dist + pb ----
    {
        float lx = lig_pos[cl * 3 + 0];
        float ly = lig_pos[cl * 3 + 1];
        float lz = lig_pos[cl * 3 + 2];
        for (int idx = tid; idx < 64 * 14; idx += 512) {
            int rw = idx / 14;
            int a  = idx - rw * 14;
            const float* pp = prot_pos + (size_t)(cp0 + rw) * 42 + a * 3;
            float dx = lx - pp[0];
            float dy = ly - pp[1];
            float dz = lz - pp[2];
            out_dist[(size_t)(m0 + rw) * 14 + a] = sqrtf(dx * dx + dy * dy + dz * dz);
        }
        if (tid < 64) out_pb[m0 + tid] = (float)b;
    }
    __syncthreads();

    // ---- pi stores (wf<2) ----
    if (wf < 2) {
        float inv[2][4];
        #pragma unroll
        for (int rs = 0; rs < 2; ++rs)
            #pragma unroll
            for (int rg = 0; rg < 4; ++rg) {
                int rl = rowB + rs * 16 + g * 4 + rg;
                inv[rs][rg] = 1.f / (psum[0][rl] + psum[1][rl]);
            }
        #pragma unroll
        for (int i = 0; i < 7; ++i) {
            int fn = fnBase + i;
            if (fn < 9) {
                int col = fn * 16 + cGrp;
                if (col < 140) {
                    #pragma unroll
                    for (int rs = 0; rs < 2; ++rs)
                        #pragma unroll
                        for (int rg = 0; rg < 4; ++rg)
                            out_pi[(size_t)(m0 + rowB + rs * 16 + g * 4 + rg) * 140 + col] =
                                acc[i][rs][rg] * inv[rs][rg];
                }
            }
        }
    }
}

// ---------------------------------------------------------------------------
// Tail: atom_types [768,17] and bond_types [2048,5]
// ---------------------------------------------------------------------------
__global__ void tail_kernel(const float* __restrict__ h_l,
                            const int* __restrict__ esrc, const int* __restrict__ edst,
                            const float* __restrict__ Wat, const float* __restrict__ bat,
                            const float* __restrict__ Wbt, const float* __restrict__ bbt,
                            float* __restrict__ out_at, float* __restrict__ out_bt) {
    int t = blockIdx.x * 256 + threadIdx.x;
    if (t < 768 * 17) {
        int row = t / 17, c = t % 17;
        const float* hr = h_l + (size_t)row * 128;
        float s = bat[c];
        #pragma unroll 4
        for (int k = 0; k < 128; ++k) s += hr[k] * Wat[k * 17 + c];
        out_at[t] = s;
    } else {
        int t2 = t - 768 * 17;
        if (t2 < 2048 * 5) {
            int e = t2 / 5, c = t2 % 5;
            const float* hs = h_l + (size_t)esrc[e] * 128;
            const float* hd = h_l + (size_t)edst[e] * 128;
            float s = bbt[c];
            #pragma unroll 4
            for (int k = 0; k < 128; ++k)
                s += hs[k] * Wbt[k * 5 + c] + hd[k] * Wbt[(k + 128) * 5 + c];
            out_bt[t2] = s;
        }
    }
}

// ---------------------------------------------------------------------------
extern "C" void kernel_launch(void* const* d_in, const int* in_sizes, int n_in,
                              void* d_out, int out_size, void* d_ws, size_t ws_size,
                              hipStream_t stream) {
    const float* h_l      = (const float*)d_in[0];
    const float* h_p      = (const float*)d_in[1];
    const float* lig_pos  = (const float*)d_in[2];
    const float* prot_pos = (const float*)d_in[3];
    const int*   esrc     = (const int*)d_in[4];
    const int*   edst     = (const int*)d_in[5];
    const float* W1    = (const float*)d_in[12];
    const float* b1    = (const float*)d_in[13];
    const float* gamma = (const float*)d_in[14];
    const float* beta  = (const float*)d_in[15];
    const float* rmean = (const float*)d_in[16];
    const float* rvar  = (const float*)d_in[17];
    const float* Wpi   = (const float*)d_in[18];
    const float* bpi   = (const float*)d_in[19];
    const float* Wsig  = (const float*)d_in[20];
    const float* bsig  = (const float*)d_in[21];
    const float* Wmu   = (const float*)d_in[22];
    const float* bmu   = (const float*)d_in[23];
    const float* Wat   = (const float*)d_in[24];
    const float* bat   = (const float*)d_in[25];
    const float* Wbt   = (const float*)d_in[26];
    const float* bbt   = (const float*)d_in[27];

    char* ws = (char*)d_ws;
    unsigned short* W1T = (unsigned short*)(ws + 0);
    unsigned short* W2T = (unsigned short*)(ws + 131072);
    float*          b2  = (float*)(ws + 360448);
    float*          a1v = (float*)(ws + 362240);
    float*          csv = (float*)(ws + 363264);
    float*          Lq  = (float*)(ws + 364544);
    float*          Pq  = (float*)(ws + 1150976);

    float* out = (float*)d_out;
    const size_t M = M_TOT;
    float* out_pi   = out;
    float* out_sig  = out + M * 140;
    float* out_mu   = out + 2 * M * 140;
    float* out_dist = out + 3 * M * 140;
    float* out_at   = out + 3 * M * 140 + M * 14;
    float* out_bt   = out_at + 768 * 17;
    float* out_pb   = out_bt + 2048 * 5;

    hipLaunchKernelGGL(prep_weights, dim3(448), dim3(256), 0, stream,
                       W1, b1, gamma, beta, rmean, rvar,
                       Wpi, bpi, Wsig, bsig, Wmu, bmu,
                       W1T, W2T, b2, a1v, csv);

    hipLaunchKernelGGL(node_gemm, dim3((768 + 6144) / 64), dim3(256), 0, stream,
                       h_l, h_p, W1T, a1v, csv, Lq, Pq);

    hipLaunchKernelGGL(pair_kernel, dim3(M_TOT / 64), dim3(512), 0, stream,
                       Lq, Pq, W2T, b2, lig_pos, prot_pos,
                       out_pi, out_sig, out_mu, out_dist, out_pb);

    hipLaunchKernelGGL(tail_kernel, dim3((768 * 17 + 2048 * 5 + 255) / 256), dim3(256), 0, stream,
                       h_l, esrc, edst, Wat, bat, Wbt, bbt, out_at, out_bt);
}

// Round 4
// 339.021 us; speedup vs baseline: 1.3127x; 1.3127x over previous
//
#include <hip/hip_runtime.h>

// ---------------------------------------------------------------------------
// MDNV2 fused kernels for MI355X (gfx950) — round 4
//
// vs round 3: pair_kernel restructured around LDS-resident weights.
//  * N split in 2 halves of 224 cols (blockIdx.y); W2 half (114 KB, packed in
//    MFMA-fragment order by prep) staged into LDS ONCE per block.
//  * M=256 rows/block, 8 waves x 32 rows, mfma_f32_32x32x16_bf16,
//    X = elu(Lq+Pq) held fully in registers (64 VGPR), acc 7 x f32x16.
//  * K-loop is pure ds_read+MFMA, ZERO barriers (1 barrier total per block).
//  * pi (cols 0..139) entirely in half 0 -> softmax wave-local (shuffles only).
//  * Stores: per store instr, two 128-B contiguous runs.
// ---------------------------------------------------------------------------

typedef __attribute__((ext_vector_type(8))) short bf16x8;
typedef __attribute__((ext_vector_type(4))) float f32x4;
typedef __attribute__((ext_vector_type(16))) float f32x16;
typedef __attribute__((ext_vector_type(4))) unsigned int u32x4;

#define M_TOT 327680

__device__ __forceinline__ unsigned short f2bf(float f) {
    union { float f; unsigned int u; } v; v.f = f;
    unsigned int r = (v.u + 0x7FFFu + ((v.u >> 16) & 1u)) >> 16;  // RNE
    return (unsigned short)r;
}

__device__ __forceinline__ float eluf(float y) {
    return fmaxf(y, 0.f) + __expf(fminf(y, 0.f)) - 1.f;
}

__device__ __forceinline__ unsigned packbf(float y0, float y1) {
    return (__float_as_uint(y1) & 0xFFFF0000u) | (__float_as_uint(y0) >> 16);
}

// ---------------------------------------------------------------------------
// prep_weights: ws layout (bytes):
//   W1T @0       : [256 n][256 k] bf16                              131072
//   W2s @131072  : packed [nh 2][fk 8][frag 7][c 4][n 32][j 8] bf16 229376
//   b2  @360448  : [448] f32 (pi@0, sig@144, mu@288, pads zero)
//   a1  @362240  : [256] f32
//   cs  @363264  : [256] f32
//   Lq  @364544  : [768][256] f32
//   Pq  @1150976 : [6144][256] f32
// W2s element (nh,fk,frag,c,n,j) = W2[k][nG],
//   k = fk*32 + (c>>1)*16 + (c&1)*8 + j,  nG = nh*224 + frag*32 + n.
// ---------------------------------------------------------------------------
__global__ void prep_weights(const float* __restrict__ W1, const float* __restrict__ b1,
                             const float* __restrict__ gamma, const float* __restrict__ beta,
                             const float* __restrict__ rmean, const float* __restrict__ rvar,
                             const float* __restrict__ Wpi, const float* __restrict__ bpi,
                             const float* __restrict__ Wsig, const float* __restrict__ bsig,
                             const float* __restrict__ Wmu, const float* __restrict__ bmu,
                             unsigned short* __restrict__ W1T, unsigned short* __restrict__ W2s,
                             float* __restrict__ b2, float* __restrict__ a1v, float* __restrict__ csv) {
    int idx = blockIdx.x * 256 + threadIdx.x;          // grid 448 -> 114688 threads
    {
        int j  = idx & 7;
        int n5 = (idx >> 3) & 31;
        int c  = (idx >> 8) & 3;
        int t  = idx >> 10;                            // 0..111
        int frag = t % 7;
        int t2   = t / 7;                              // 0..15
        int fk   = t2 & 7;
        int nh   = t2 >> 3;
        int k  = fk * 32 + ((c >> 1) << 4) + ((c & 1) << 3) + j;
        int nG = nh * 224 + frag * 32 + n5;
        float v = 0.f;
        if (nG < 140)                    v = Wpi [k * 140 + nG];
        else if (nG >= 144 && nG < 284)  v = Wsig[k * 140 + (nG - 144)];
        else if (nG >= 288 && nG < 428)  v = Wmu [k * 140 + (nG - 288)];
        W2s[idx] = f2bf(v);
    }
    if (idx < 256 * 256) {                             // W1T[n][k] = W1[k][n]
        int n = idx >> 8, k = idx & 255;
        W1T[idx] = f2bf(W1[k * 256 + n]);
    }
    if (idx < 448) {
        float v = 0.f;
        if (idx < 140)                      v = bpi [idx];
        else if (idx >= 144 && idx < 284)   v = bsig[idx - 144];
        else if (idx >= 288 && idx < 428)   v = bmu [idx - 288];
        b2[idx] = v;
    }
    if (idx < 256) {
        float s = gamma[idx] * rsqrtf(rvar[idx] + 1e-5f);
        a1v[idx] = s;
        csv[idx] = s * (b1[idx] - rmean[idx]) + beta[idx];
    }
}

// ---------------------------------------------------------------------------
// node_gemm: Lq (BN shift folded) / Pq (scale only) -- unchanged from R2/R3
// ---------------------------------------------------------------------------
__global__ __launch_bounds__(256, 2) void node_gemm(
        const float* __restrict__ h_l, const float* __restrict__ h_p,
        const unsigned short* __restrict__ W1T,
        const float* __restrict__ a1v, const float* __restrict__ csv,
        float* __restrict__ Lq, float* __restrict__ Pq) {
    const int tid = threadIdx.x, lane = tid & 63, w = tid >> 6;
    const int cGrp = lane & 15, g = lane >> 4;
    const int row0 = blockIdx.x * 64;
    const bool isLig = row0 < 768;
    const float* src = isLig ? (h_l + (size_t)row0 * 128) : (h_p + (size_t)(row0 - 768) * 128);
    float*       dst = isLig ? (Lq + (size_t)row0 * 256) : (Pq + (size_t)(row0 - 768) * 256);
    const int koff = isLig ? 0 : 128;

    f32x4 acc[16];
    #pragma unroll
    for (int fn = 0; fn < 16; ++fn) acc[fn] = (f32x4){0.f, 0.f, 0.f, 0.f};

    #pragma unroll
    for (int fk = 0; fk < 4; ++fk) {
        const float* ap = src + (size_t)(w * 16 + cGrp) * 128 + fk * 32 + g * 8;
        f32x4 qa = *(const f32x4*)ap;
        f32x4 qb = *(const f32x4*)(ap + 4);
        bf16x8 af;
        af[0] = (short)f2bf(qa[0]); af[1] = (short)f2bf(qa[1]);
        af[2] = (short)f2bf(qa[2]); af[3] = (short)f2bf(qa[3]);
        af[4] = (short)f2bf(qb[0]); af[5] = (short)f2bf(qb[1]);
        af[6] = (short)f2bf(qb[2]); af[7] = (short)f2bf(qb[3]);
        #pragma unroll
        for (int fn = 0; fn < 16; ++fn) {
            bf16x8 bf = *(const bf16x8*)(W1T + (fn * 16 + cGrp) * 256 + koff + fk * 32 + g * 8);
            acc[fn] = __builtin_amdgcn_mfma_f32_16x16x32_bf16(af, bf, acc[fn], 0, 0, 0);
        }
    }
    #pragma unroll
    for (int fn = 0; fn < 16; ++fn) {
        int h = fn * 16 + cGrp;
        float s = a1v[h];
        float c0 = isLig ? csv[h] : 0.f;
        #pragma unroll
        for (int rg = 0; rg < 4; ++rg)
            dst[(size_t)(w * 16 + g * 4 + rg) * 256 + h] = s * acc[fn][rg] + c0;
    }
}

// ---------------------------------------------------------------------------
// pair_kernel: grid (1280, 2). Block = 256 pair-rows x 224-col N-half.
// ---------------------------------------------------------------------------
__global__ __launch_bounds__(512, 2) void pair_kernel(
        const float* __restrict__ Lq, const float* __restrict__ Pq,
        const unsigned short* __restrict__ W2s, const float* __restrict__ b2p,
        const float* __restrict__ lig_pos, const float* __restrict__ prot_pos,
        float* __restrict__ out_pi, float* __restrict__ out_sig, float* __restrict__ out_mu,
        float* __restrict__ out_dist, float* __restrict__ out_pb) {

    __shared__ __align__(16) unsigned short Bs[57344];   // 114688 B, whole-block lifetime

    const int tid = threadIdx.x, lane = tid & 63, w = tid >> 6;
    const int ln31 = lane & 31, hi = lane >> 5;
    const int nh = blockIdx.y;
    const int m0 = blockIdx.x * 256;

    // ---- closed-form pair decode (tile-uniform batch/ligand, contiguous cp) ----
    unsigned int P = (unsigned int)m0 / 40960u;
    unsigned int r = (unsigned int)m0 % 40960u;
    int b, cl, cp0;
    if (r < 8192u) {            // even batch: one ligand row's full 256 prot
        b = 2 * (int)P; cl = 96 * (int)P + (int)(r >> 8); cp0 = 768 * (int)P;
    } else {                    // odd batch: half of a ligand row's 512 prot
        unsigned int rr = r - 8192u;
        b = 2 * (int)P + 1; cl = 96 * (int)P + 32 + (int)(rr >> 9);
        cp0 = 768 * (int)P + 256 + (int)(rr & 511u);
    }

    // ---- issue weight-staging loads early (consumed after X phase) ----
    const unsigned short* wsrc = W2s + (size_t)nh * 57344;
    bf16x8 stg[14];
    #pragma unroll
    for (int i = 0; i < 14; ++i)
        stg[i] = *(const bf16x8*)(wsrc + (size_t)(tid + 512 * i) * 8);

    // ---- X = elu(Lq[cl] + Pq[cp]) into registers (A-fragment layout) ----
    // lane owns row xrow; k positions s*16 + hi*8 + j
    const int xrow = w * 32 + ln31;
    const float* pqp = Pq + (size_t)(cp0 + xrow) * 256 + hi * 8;
    const float* lqp = Lq + (size_t)cl * 256 + hi * 8;
    bf16x8 Xr[16];
    #pragma unroll
    for (int s = 0; s < 16; ++s) {
        f32x4 p0 = *(const f32x4*)(pqp + s * 16);
        f32x4 p1 = *(const f32x4*)(pqp + s * 16 + 4);
        f32x4 l0 = *(const f32x4*)(lqp + s * 16);
        f32x4 l1 = *(const f32x4*)(lqp + s * 16 + 4);
        float y0 = eluf(p0[0] + l0[0]), y1 = eluf(p0[1] + l0[1]);
        float y2 = eluf(p0[2] + l0[2]), y3 = eluf(p0[3] + l0[3]);
        float y4 = eluf(p1[0] + l1[0]), y5 = eluf(p1[1] + l1[1]);
        float y6 = eluf(p1[2] + l1[2]), y7 = eluf(p1[3] + l1[3]);
        union { u32x4 u; bf16x8 h; } cv;
        cv.u[0] = packbf(y0, y1); cv.u[1] = packbf(y2, y3);
        cv.u[2] = packbf(y4, y5); cv.u[3] = packbf(y6, y7);
        Xr[s] = cv.h;
    }

    // ---- write staged weights to LDS, single barrier ----
    #pragma unroll
    for (int i = 0; i < 14; ++i)
        *(bf16x8*)(Bs + (size_t)(tid + 512 * i) * 8) = stg[i];
    __syncthreads();

    // ---- K-loop: pure ds_read + MFMA, no barriers ----
    f32x16 acc[7];
    #pragma unroll
    for (int f = 0; f < 7; ++f)
        #pragma unroll
        for (int q = 0; q < 16; ++q) acc[f][q] = 0.f;

    #pragma unroll
    for (int s = 0; s < 16; ++s) {
        const int base = (s >> 1) * 7168 + ((s & 1) * 2 + hi) * 256 + ln31 * 8;
        #pragma unroll
        for (int f = 0; f < 7; ++f) {
            bf16x8 bf = *(const bf16x8*)(Bs + base + f * 1024);
            acc[f] = __builtin_amdgcn_mfma_f32_32x32x16_bf16(Xr[s], bf, acc[f], 0, 0, 0);
        }
    }

    // ---- bias ----
    float bb[7];
    #pragma unroll
    for (int f = 0; f < 7; ++f) bb[f] = b2p[nh * 224 + f * 32 + ln31];
    #pragma unroll
    for (int f = 0; f < 7; ++f)
        #pragma unroll
        for (int q = 0; q < 16; ++q) acc[f][q] += bb[f];

    if (nh == 0) {
        // ---- pi softmax (cols 0..139 all in this half), wave-local ----
        const bool v4 = (ln31 < 12);
        #pragma unroll
        for (int q = 0; q < 16; ++q) {
            float m01 = fmaxf(acc[0][q], acc[1][q]);
            float m23 = fmaxf(acc[2][q], acc[3][q]);
            float mx = fmaxf(fmaxf(m01, m23), v4 ? acc[4][q] : -3.0e38f);
            #pragma unroll
            for (int d = 1; d < 32; d <<= 1) mx = fmaxf(mx, __shfl_xor(mx, d, 64));
            float e0 = __expf(acc[0][q] - mx), e1 = __expf(acc[1][q] - mx);
            float e2 = __expf(acc[2][q] - mx), e3 = __expf(acc[3][q] - mx);
            float e4 = v4 ? __expf(acc[4][q] - mx) : 0.f;
            float sm = e0 + e1 + e2 + e3 + e4;
            #pragma unroll
            for (int d = 1; d < 32; d <<= 1) sm += __shfl_xor(sm, d, 64);
            float inv = 1.f / sm;
            acc[0][q] = e0 * inv; acc[1][q] = e1 * inv;
            acc[2][q] = e2 * inv; acc[3][q] = e3 * inv;
            if (v4) acc[4][q] = e4 * inv;            // keep sig lanes intact
        }
        #pragma unroll
        for (int q = 0; q < 16; ++q) {
            const int gr = m0 + w * 32 + (q & 3) + 8 * (q >> 2) + 4 * hi;
            float* prow = out_pi + (size_t)gr * 140;
            prow[ln31]       = acc[0][q];
            prow[32 + ln31]  = acc[1][q];
            prow[64 + ln31]  = acc[2][q];
            prow[96 + ln31]  = acc[3][q];
            if (v4) prow[128 + ln31] = acc[4][q];
            float* srow = out_sig + (size_t)gr * 140;
            if (ln31 >= 16) srow[ln31 - 16] = eluf(acc[4][q]) + 1.1f;
            srow[16 + ln31] = eluf(acc[5][q]) + 1.1f;
            srow[48 + ln31] = eluf(acc[6][q]) + 1.1f;
        }
    } else {
        #pragma unroll
        for (int q = 0; q < 16; ++q) {
            const int gr = m0 + w * 32 + (q & 3) + 8 * (q >> 2) + 4 * hi;
            float* srow = out_sig + (size_t)gr * 140;
            srow[80 + ln31] = eluf(acc[0][q]) + 1.1f;
            if (ln31 < 28) srow[112 + ln31] = eluf(acc[1][q]) + 1.1f;
            float* mrow = out_mu + (size_t)gr * 140;
            mrow[ln31]      = eluf(acc[2][q]) + 1.0f;
            mrow[32 + ln31] = eluf(acc[3][q]) + 1.0f;
            mrow[64 + ln31] = eluf(acc[4][q]) + 1.0f;
            mrow[96 + ln31] = eluf(acc[5][q]) + 1.0f;
            if (ln31 < 12) mrow[128 + ln31] = eluf(acc[6][q]) + 1.0f;
        }
        // ---- dist + pb (done once, by nh=1 blocks) ----
        float lx = lig_pos[cl * 3 + 0];
        float ly = lig_pos[cl * 3 + 1];
        float lz = lig_pos[cl * 3 + 2];
        #pragma unroll
        for (int i = 0; i < 7; ++i) {
            int idx = tid + 512 * i;                  // < 3584
            int rw = idx / 14, a = idx - rw * 14;
            const float* pp = prot_pos + (size_t)(cp0 + rw) * 42 + a * 3;
            float dx = lx - pp[0], dy = ly - pp[1], dz = lz - pp[2];
            out_dist[(size_t)(m0 + rw) * 14 + a] = sqrtf(dx * dx + dy * dy + dz * dz);
        }
        if (tid < 256) out_pb[m0 + tid] = (float)b;
    }
}

// ---------------------------------------------------------------------------
// Tail: atom_types [768,17] and bond_types [2048,5]
// ---------------------------------------------------------------------------
__global__ void tail_kernel(const float* __restrict__ h_l,
                            const int* __restrict__ esrc, const int* __restrict__ edst,
                            const float* __restrict__ Wat, const float* __restrict__ bat,
                            const float* __restrict__ Wbt, const float* __restrict__ bbt,
                            float* __restrict__ out_at, float* __restrict__ out_bt) {
    int t = blockIdx.x * 256 + threadIdx.x;
    if (t < 768 * 17) {
        int row = t / 17, c = t % 17;
        const float* hr = h_l + (size_t)row * 128;
        float s = bat[c];
        #pragma unroll 4
        for (int k = 0; k < 128; ++k) s += hr[k] * Wat[k * 17 + c];
        out_at[t] = s;
    } else {
        int t2 = t - 768 * 17;
        if (t2 < 2048 * 5) {
            int e = t2 / 5, c = t2 % 5;
            const float* hs = h_l + (size_t)esrc[e] * 128;
            const float* hd = h_l + (size_t)edst[e] * 128;
            float s = bbt[c];
            #pragma unroll 4
            for (int k = 0; k < 128; ++k)
                s += hs[k] * Wbt[k * 5 + c] + hd[k] * Wbt[(k + 128) * 5 + c];
            out_bt[t2] = s;
        }
    }
}

// ---------------------------------------------------------------------------
extern "C" void kernel_launch(void* const* d_in, const int* in_sizes, int n_in,
                              void* d_out, int out_size, void* d_ws, size_t ws_size,
                              hipStream_t stream) {
    const float* h_l      = (const float*)d_in[0];
    const float* h_p      = (const float*)d_in[1];
    const float* lig_pos  = (const float*)d_in[2];
    const float* prot_pos = (const float*)d_in[3];
    const int*   esrc     = (const int*)d_in[4];
    const int*   edst     = (const int*)d_in[5];
    const float* W1    = (const float*)d_in[12];
    const float* b1    = (const float*)d_in[13];
    const float* gamma = (const float*)d_in[14];
    const float* beta  = (const float*)d_in[15];
    const float* rmean = (const float*)d_in[16];
    const float* rvar  = (const float*)d_in[17];
    const float* Wpi   = (const float*)d_in[18];
    const float* bpi   = (const float*)d_in[19];
    const float* Wsig  = (const float*)d_in[20];
    const float* bsig  = (const float*)d_in[21];
    const float* Wmu   = (const float*)d_in[22];
    const float* bmu   = (const float*)d_in[23];
    const float* Wat   = (const float*)d_in[24];
    const float* bat   = (const float*)d_in[25];
    const float* Wbt   = (const float*)d_in[26];
    const float* bbt   = (const float*)d_in[27];

    char* ws = (char*)d_ws;
    unsigned short* W1T = (unsigned short*)(ws + 0);
    unsigned short* W2s = (unsigned short*)(ws + 131072);
    float*          b2  = (float*)(ws + 360448);
    float*          a1v = (float*)(ws + 362240);
    float*          csv = (float*)(ws + 363264);
    float*          Lq  = (float*)(ws + 364544);
    float*          Pq  = (float*)(ws + 1150976);

    float* out = (float*)d_out;
    const size_t M = M_TOT;
    float* out_pi   = out;
    float* out_sig  = out + M * 140;
    float* out_mu   = out + 2 * M * 140;
    float* out_dist = out + 3 * M * 140;
    float* out_at   = out + 3 * M * 140 + M * 14;
    float* out_bt   = out_at + 768 * 17;
    float* out_pb   = out_bt + 2048 * 5;

    hipLaunchKernelGGL(prep_weights, dim3(448), dim3(256), 0, stream,
                       W1, b1, gamma, beta, rmean, rvar,
                       Wpi, bpi, Wsig, bsig, Wmu, bmu,
                       W1T, W2s, b2, a1v, csv);

    hipLaunchKernelGGL(node_gemm, dim3((768 + 6144) / 64), dim3(256), 0, stream,
                       h_l, h_p, W1T, a1v, csv, Lq, Pq);

    hipLaunchKernelGGL(pair_kernel, dim3(M_TOT / 256, 2), dim3(512), 0, stream,
                       Lq, Pq, W2s, b2, lig_pos, prot_pos,
                       out_pi, out_sig, out_mu, out_dist, out_pb);

    hipLaunchKernelGGL(tail_kernel, dim3((768 * 17 + 2048 * 5 + 255) / 256), dim3(256), 0, stream,
                       h_l, esrc, edst, Wat, bat, Wbt, bbt, out_at, out_bt);
}